// Round 1
// 1648.988 us; speedup vs baseline: 2.1089x; 2.1089x over previous
//
#include <hip/hip_runtime.h>

// Problem: n=32, c1=c2=512, hw=4096. fp32 in/out.
// out1 = alpha*softmax_row(att) @ x2 + x1
// out2 = beta *softmax_col(att)^T-weights @ x1 + x2
// att[i][j] = <x1_i, x2_j> / (||x1_i|| ||x2_j||)
//
// All three 68.7-GFLOP GEMMs now run on bf16 MFMA (16x16x32) with fp32
// accumulation; fp32 operands are converted to bf16 (truncation) during LDS
// staging. Epilogue adds X in exact fp32.

#define N_B 32
#define C_  512
#define HW_ 4096

typedef float f32x4 __attribute__((ext_vector_type(4)));
typedef short s16x8 __attribute__((ext_vector_type(8)));   // 8 bf16 = 4 VGPRs

__device__ __forceinline__ unsigned pack_bf2(float lo, float hi) {
    unsigned a = __builtin_bit_cast(unsigned, lo);
    unsigned b = __builtin_bit_cast(unsigned, hi);
    return (a >> 16) | (b & 0xFFFF0000u);   // [hi.bf16 | lo.bf16]
}
__device__ __forceinline__ unsigned short f2bf(float f) {
    return (unsigned short)(__builtin_bit_cast(unsigned, f) >> 16);
}

// ---------------- row inverse L2 norm: one block per (n,c) row ----------------
__global__ void row_inv_norm(const float* __restrict__ x, float* __restrict__ invn) {
    const size_t row = blockIdx.x;               // 0 .. 32*512-1
    const float* p = x + row * (size_t)HW_;
    const int t = threadIdx.x;                   // 256 threads
    float ss = 0.f;
#pragma unroll
    for (int jj = 0; jj < 4; ++jj) {
        float4 v = *(const float4*)(p + 4 * (t + 256 * jj));
        ss += v.x * v.x + v.y * v.y + v.z * v.z + v.w * v.w;
    }
    __shared__ float red[256];
    red[t] = ss;
    __syncthreads();
    for (int s = 128; s > 0; s >>= 1) {
        if (t < s) red[t] += red[t + s];
        __syncthreads();
    }
    if (t == 0) {
        float nrm = sqrtf(red[0]);
        invn[row] = 1.0f / fmaxf(nrm, 1e-12f);
    }
}

// ---------------- attention GEMM (MFMA): att = diag(inv1)(x1 x2^T)diag(inv2) --
// 128x128 block tile, BK=64, 256 threads = 4 waves (2x2), 64x64 per wave.
// Both operands are K-inner fp32; staged to bf16 LDS [128 rows][64 k] with
// XOR-chunk swizzle (byte ^= (row&7)<<4) so ds_read_b128 frag loads are
// conflict-free (2 lanes/bank).
__global__ __launch_bounds__(256) void attn_gemm_mfma(
    const float* __restrict__ x1, const float* __restrict__ x2,
    const float* __restrict__ inv1, const float* __restrict__ inv2,
    float* __restrict__ att)
{
    const int n  = blockIdx.z;
    const int j0 = blockIdx.x * 128;
    const int m0 = blockIdx.y * 128;
    const float* Ag = x1 + (size_t)n * C_ * HW_;
    const float* Bg = x2 + (size_t)n * C_ * HW_;

    __shared__ char As[128 * 128];   // 128 rows x 64 bf16 (128B/row)
    __shared__ char Bs[128 * 128];

    const int t    = threadIdx.x;
    const int lane = t & 63;
    const int w    = t >> 6;
    const int wr   = (w >> 1) * 64;
    const int wc   = (w & 1) * 64;
    const int fr   = lane & 15;      // frag row/col within 16
    const int fg   = lane >> 4;      // frag k-group (8 bf16 each)

    int srow[4], sslot[4], schunk[4];
#pragma unroll
    for (int p = 0; p < 4; ++p) {
        int idx   = p * 256 + t;     // 1024 16B-slots per tile
        srow[p]   = idx >> 3;        // 0..127
        sslot[p]  = idx & 7;         // dest slot in row
        schunk[p] = sslot[p] ^ (srow[p] & 7);  // source chunk (swizzle)
    }

    float a_st[4][8], b_st[4][8];
    f32x4 acc[4][4];
#pragma unroll
    for (int i = 0; i < 4; ++i)
#pragma unroll
        for (int j = 0; j < 4; ++j) acc[i][j] = (f32x4){0.f, 0.f, 0.f, 0.f};

    auto load_tiles = [&](int k0) {
#pragma unroll
        for (int p = 0; p < 4; ++p) {
            const float* ga = Ag + (size_t)(m0 + srow[p]) * HW_ + k0 + schunk[p] * 8;
            const float* gb = Bg + (size_t)(j0 + srow[p]) * HW_ + k0 + schunk[p] * 8;
            *(float4*)&a_st[p][0] = *(const float4*)ga;
            *(float4*)&a_st[p][4] = *(const float4*)(ga + 4);
            *(float4*)&b_st[p][0] = *(const float4*)gb;
            *(float4*)&b_st[p][4] = *(const float4*)(gb + 4);
        }
    };
    auto store_tiles = [&]() {
#pragma unroll
        for (int p = 0; p < 4; ++p) {
            uint4 pa, pb;
            pa.x = pack_bf2(a_st[p][0], a_st[p][1]);
            pa.y = pack_bf2(a_st[p][2], a_st[p][3]);
            pa.z = pack_bf2(a_st[p][4], a_st[p][5]);
            pa.w = pack_bf2(a_st[p][6], a_st[p][7]);
            pb.x = pack_bf2(b_st[p][0], b_st[p][1]);
            pb.y = pack_bf2(b_st[p][2], b_st[p][3]);
            pb.z = pack_bf2(b_st[p][4], b_st[p][5]);
            pb.w = pack_bf2(b_st[p][6], b_st[p][7]);
            const int off = srow[p] * 128 + sslot[p] * 16;
            *(uint4*)(As + off) = pa;
            *(uint4*)(Bs + off) = pb;
        }
    };
    auto compute = [&]() {
#pragma unroll
        for (int kk = 0; kk < 2; ++kk) {
            s16x8 af[4], bfv[4];
#pragma unroll
            for (int mi = 0; mi < 4; ++mi) {
                int row  = wr + mi * 16 + fr;
                int phys = (kk * 64 + fg * 16) ^ ((row & 7) << 4);
                af[mi] = __builtin_bit_cast(s16x8, *(const uint4*)(As + row * 128 + phys));
            }
#pragma unroll
            for (int ni = 0; ni < 4; ++ni) {
                int row  = wc + ni * 16 + fr;
                int phys = (kk * 64 + fg * 16) ^ ((row & 7) << 4);
                bfv[ni] = __builtin_bit_cast(s16x8, *(const uint4*)(Bs + row * 128 + phys));
            }
#pragma unroll
            for (int mi = 0; mi < 4; ++mi)
#pragma unroll
                for (int ni = 0; ni < 4; ++ni)
                    acc[mi][ni] = __builtin_amdgcn_mfma_f32_16x16x32_bf16(
                        af[mi], bfv[ni], acc[mi][ni], 0, 0, 0);
        }
    };

    load_tiles(0);
#pragma unroll 1
    for (int k0 = 0; k0 < HW_; k0 += 64) {
        __syncthreads();                 // prev compute done (LDS reusable)
        store_tiles();
        __syncthreads();                 // tiles visible
        if (k0 + 64 < HW_) load_tiles(k0 + 64);   // overlap with MFMA
        compute();
    }

    // epilogue: scale by inv1[i]*inv2[j], write fp32 att
    float s2v[4];
#pragma unroll
    for (int ni = 0; ni < 4; ++ni) s2v[ni] = inv2[n * C_ + j0 + wc + ni * 16 + fr];
#pragma unroll
    for (int mi = 0; mi < 4; ++mi)
#pragma unroll
        for (int r = 0; r < 4; ++r) {
            int m = m0 + wr + mi * 16 + fg * 4 + r;
            float s1 = inv1[n * C_ + m];
            float* orow = att + ((size_t)n * C_ + m) * C_ + j0 + wc;
#pragma unroll
            for (int ni = 0; ni < 4; ++ni)
                orow[ni * 16 + fr] = acc[mi][ni][r] * s1 * s2v[ni];
        }
}

// ---------------- column softmax (over i), writes bf16 attn2[n][j][i] ---------
__global__ void col_softmax_bf16(const float* __restrict__ att,
                                 unsigned short* __restrict__ attn2b) {
    const int n  = blockIdx.y;
    const int j0 = blockIdx.x * 64;
    const int t  = threadIdx.x;
    const int col = j0 + (t & 63);
    const int sl  = t >> 6;                      // 0..3
    const float* base = att + (size_t)n * C_ * C_;

    float m = -INFINITY, l = 0.f;
    for (int i = sl * 128; i < sl * 128 + 128; ++i) {
        float v = base[(size_t)i * C_ + col];
        float mn = fmaxf(m, v);
        l = l * __expf(m - mn) + __expf(v - mn);
        m = mn;
    }
    __shared__ float ms[4][64], ls[4][64];
    ms[sl][t & 63] = m;
    ls[sl][t & 63] = l;
    __syncthreads();
    float M = fmaxf(fmaxf(ms[0][t & 63], ms[1][t & 63]),
                    fmaxf(ms[2][t & 63], ms[3][t & 63]));
    float L = 0.f;
#pragma unroll
    for (int s = 0; s < 4; ++s) L += ls[s][t & 63] * __expf(ms[s][t & 63] - M);
    const float inv = 1.0f / L;
    unsigned short* outp = attn2b + ((size_t)n * C_ + col) * C_;
    for (int i = sl * 128; i < sl * 128 + 128; ++i)
        outp[i] = f2bf(__expf(base[(size_t)i * C_ + col] - M) * inv);
}

// ---------------- row softmax, rewrites att row IN PLACE as bf16 (pitch 1024) -
__global__ void row_softmax_bf16(float* __restrict__ att) {
    const size_t row = blockIdx.x;               // n*512 + i
    float* p = att + row * (size_t)C_;
    const int t = threadIdx.x;                   // 256
    float2 v = *(const float2*)(p + 2 * t);
    __shared__ float red[256];
    red[t] = fmaxf(v.x, v.y);
    __syncthreads();
    for (int s = 128; s > 0; s >>= 1) {
        if (t < s) red[t] = fmaxf(red[t], red[t + s]);
        __syncthreads();
    }
    const float M = red[0];
    __syncthreads();
    float e0 = __expf(v.x - M), e1 = __expf(v.y - M);
    red[t] = e0 + e1;
    __syncthreads();
    for (int s = 128; s > 0; s >>= 1) {
        if (t < s) red[t] += red[t + s];
        __syncthreads();
    }
    const float inv = 1.0f / red[0];
    // bf16 row occupies the first 1024B of this row's 2048B slot; all loads
    // of this row happened before the first barrier -> no in-place hazard.
    ((unsigned*)p)[t] = pack_bf2(e0 * inv, e1 * inv);
}

// ---------------- stage-2 GEMM + epilogue: out = sc*(A@B) + X -----------------
// A: bf16 [512 x 512] attention weights, row-major with pitch pitchA (elems).
// B: fp32 [K=512][N=4096] row-major (x1 or x2) -- K-outer, transposed while
//    staging into LDS Bs[128 s][72 bf16] (144B pitch: writes AND ds_read_b128
//    frag reads are bank-conflict-ideal; 144 % 16 == 0 keeps b128 aligned).
// M=512, N=4096, K=512. 128x128 tile, BK=64, 8 K-steps, 4 waves.
__global__ __launch_bounds__(256) void gemm_epi_mfma(
    const unsigned short* __restrict__ Aall, const int pitchA,
    const float* __restrict__ Ball, const float* __restrict__ Xall,
    const float* __restrict__ scal, float* __restrict__ outAll)
{
    const int n  = blockIdx.z;
    const int s0 = blockIdx.x * 128;             // N
    const int m0 = blockIdx.y * 128;             // M
    const unsigned short* Ag = Aall + (size_t)n * C_ * pitchA;
    const float* Bg = Ball + (size_t)n * C_ * HW_;
    const float* Xg = Xall + (size_t)n * C_ * HW_;
    float* out = outAll + (size_t)n * C_ * HW_;

    __shared__ char As[128 * 128];   // [row m][64 k] bf16, XOR-swizzled chunks
    __shared__ char Bs[128 * 144];   // [s][72 bf16] (64 used + 8 pad)

    const int t    = threadIdx.x;
    const int lane = t & 63;
    const int w    = t >> 6;
    const int wr   = (w >> 1) * 64;
    const int wc   = (w & 1) * 64;
    const int fr   = lane & 15;
    const int fg   = lane >> 4;

    uint4 a_st[4];
    float b_st[8][4];
    f32x4 acc[4][4];
#pragma unroll
    for (int i = 0; i < 4; ++i)
#pragma unroll
        for (int j = 0; j < 4; ++j) acc[i][j] = (f32x4){0.f, 0.f, 0.f, 0.f};

    auto load_a = [&](int k0) {                  // A already bf16: 16B/slot
#pragma unroll
        for (int p = 0; p < 4; ++p) {
            int idx = p * 256 + t;
            int r   = idx >> 3;
            int c   = (idx & 7) ^ (r & 7);       // swizzled source chunk
            a_st[p] = *(const uint4*)(Ag + (size_t)(m0 + r) * pitchA + k0 + c * 8);
        }
    };
    auto store_a = [&]() {
#pragma unroll
        for (int p = 0; p < 4; ++p) {
            int idx = p * 256 + t;
            *(uint4*)(As + idx * 16) = a_st[p];  // linear dest = row*128+slot*16
        }
    };
    auto load_b = [&](int k0) {                  // 4 consecutive k of one s
#pragma unroll
        for (int p = 0; p < 8; ++p) {
            int idx = p * 256 + t;               // 2048 b64-chunks
            int s   = idx & 127;
            int k4  = (idx >> 7) * 4;
            const float* g = Bg + (size_t)(k0 + k4) * HW_ + s0 + s;
#pragma unroll
            for (int e = 0; e < 4; ++e) b_st[p][e] = g[(size_t)e * HW_];
        }
    };
    auto store_b = [&]() {
#pragma unroll
        for (int p = 0; p < 8; ++p) {
            int idx = p * 256 + t;
            int s   = idx & 127;
            int k4  = (idx >> 7) * 4;
            uint2 pk;
            pk.x = pack_bf2(b_st[p][0], b_st[p][1]);
            pk.y = pack_bf2(b_st[p][2], b_st[p][3]);
            *(uint2*)(Bs + s * 144 + k4 * 2) = pk;
        }
    };
    auto compute = [&]() {
#pragma unroll
        for (int kk = 0; kk < 2; ++kk) {
            s16x8 af[4], bfv[4];
#pragma unroll
            for (int mi = 0; mi < 4; ++mi) {
                int row  = wr + mi * 16 + fr;
                int phys = (kk * 64 + fg * 16) ^ ((row & 7) << 4);
                af[mi] = __builtin_bit_cast(s16x8, *(const uint4*)(As + row * 128 + phys));
            }
#pragma unroll
            for (int ni = 0; ni < 4; ++ni) {
                int col = wc + ni * 16 + fr;
                bfv[ni] = __builtin_bit_cast(s16x8,
                    *(const uint4*)(Bs + col * 144 + kk * 64 + fg * 16));
            }
#pragma unroll
            for (int mi = 0; mi < 4; ++mi)
#pragma unroll
                for (int ni = 0; ni < 4; ++ni)
                    acc[mi][ni] = __builtin_amdgcn_mfma_f32_16x16x32_bf16(
                        af[mi], bfv[ni], acc[mi][ni], 0, 0, 0);
        }
    };

    load_a(0);
    load_b(0);
#pragma unroll 1
    for (int ks = 0; ks < 8; ++ks) {
        __syncthreads();
        store_a();
        store_b();
        __syncthreads();
        if (ks < 7) { load_a((ks + 1) * 64); load_b((ks + 1) * 64); }  // overlap
        compute();
    }

    const float sc = scal[0];
#pragma unroll
    for (int mi = 0; mi < 4; ++mi)
#pragma unroll
        for (int r = 0; r < 4; ++r) {
            int m = m0 + wr + mi * 16 + fg * 4 + r;
            const float* xrow = Xg + (size_t)m * HW_ + s0 + wc;
            float*       orow = out + (size_t)m * HW_ + s0 + wc;
#pragma unroll
            for (int ni = 0; ni < 4; ++ni)
                orow[ni * 16 + fr] = fmaf(sc, acc[mi][ni][r], xrow[ni * 16 + fr]);
        }
}

extern "C" void kernel_launch(void* const* d_in, const int* in_sizes, int n_in,
                              void* d_out, int out_size, void* d_ws, size_t ws_size,
                              hipStream_t stream) {
    const float* x1    = (const float*)d_in[0];
    const float* x2    = (const float*)d_in[1];
    const float* alpha = (const float*)d_in[2];
    const float* beta  = (const float*)d_in[3];
    float* out = (float*)d_out;

    // Workspace (33.7 MB, same proven footprint as before):
    //   inv1 | inv2 | att (32*512*512 f32, 32 MB)
    // att is consumed by both softmaxes, then its storage is reused:
    //   row_softmax rewrites each row in place as bf16 (pitch 1024 elems).
    // attn2 (bf16 [n][j][i], 16 MB) is staged at the start of the out1 region
    // and fully consumed by gemm3 BEFORE gemm2 overwrites out1 (stream order).
    float* inv1 = (float*)d_ws;
    float* inv2 = inv1 + (size_t)N_B * C_;
    float* att  = inv2 + (size_t)N_B * C_;
    unsigned short* attn1b = (unsigned short*)att;   // pitch 2*C_
    unsigned short* attn2b = (unsigned short*)d_out; // staged in out1 region
    float* out1 = out;
    float* out2 = out + (size_t)N_B * C_ * HW_;

    row_inv_norm<<<N_B * C_, 256, 0, stream>>>(x1, inv1);
    row_inv_norm<<<N_B * C_, 256, 0, stream>>>(x2, inv2);

    attn_gemm_mfma<<<dim3(4, 4, N_B), 256, 0, stream>>>(x1, x2, inv1, inv2, att);

    col_softmax_bf16<<<dim3(8, N_B), 256, 0, stream>>>(att, attn2b);
    row_softmax_bf16<<<N_B * C_, 256, 0, stream>>>(att);

    // gemm3: out2 = beta * (attn2 @ x1) + x2   (A = attn2b[j][i], pitch 512)
    gemm_epi_mfma<<<dim3(HW_ / 128, C_ / 128, N_B), 256, 0, stream>>>(
        attn2b, C_, x1, x2, beta, out2);
    // gemm2: out1 = alpha * (attn1 @ x2) + x1  (A = bf16-in-place att, pitch 1024)
    gemm_epi_mfma<<<dim3(HW_ / 128, C_ / 128, N_B), 256, 0, stream>>>(
        attn1b, 2 * C_, x2, x1, alpha, out1);
}